// Round 7
// baseline (129.895 us; speedup 1.0000x reference)
//
#include <hip/hip_runtime.h>
#include <hip/hip_bf16.h>
#include <hip/hip_fp16.h>

// SpMM: out[r] = sum_e (rows[e]==r) vals[e] * x[cols[e], :]
// rows sorted ascending (CSR-like). N=100000, E=1600000, D=48.
//
// R6 state: spmm ~40us, within ~15% of the L2-miss-rate floor given a
// 9.6 MB fp16 footprint vs 4 MB per-XCD L2 (hit ~0.42, 119 MB miss traffic
// @ ~3.4 TB/s random-sector rate).
// R7: split x by feature into two 4.8 MB halves and pin each half to a set
// of XCDs via the blockIdx%8 round-robin mapping (perf heuristic only,
// correctness-independent). Per-XCD working set 4.8 MB ~= L2 -> hit ~0.8,
// expected miss bytes ~52 MB. Cols/vals stream is read by both halves
// (streaming, cheap). fp8 rejected: predicted max error ~0.3-0.4 vs 0.3
// threshold.

#define D_FEAT 48
#define HALF_F 24       // features per half (48 B fp16 per half-row)
#define TPR 6           // threads per (row, half): 6 lanes x 4 feats
#define RPB 32          // rows per block (192/6)
#define BLOCK 192

typedef float vfloat4 __attribute__((ext_vector_type(4)));

__global__ void build_row_ptr_scatter(const int* __restrict__ rows,
                                      int* __restrict__ row_ptr,
                                      int n_edges, int n_nodes) {
    int e = blockIdx.x * blockDim.x + threadIdx.x;
    if (e >= n_edges) return;
    const int r     = rows[e];
    const int rprev = (e == 0) ? -1 : rows[e - 1];
    for (int q = rprev + 1; q <= r; ++q) row_ptr[q] = e;
    if (e == n_edges - 1) {
        for (int q = r + 1; q <= n_nodes; ++q) row_ptr[q] = n_edges;
    }
}

// One thread per 4 source floats -> one 8 B fp16 write into half 0 or 1.
__global__ void convert_x_f16_split(const float* __restrict__ x,
                                    __half* __restrict__ xh0,
                                    __half* __restrict__ xh1, int n4) {
    int i = blockIdx.x * blockDim.x + threadIdx.x;
    if (i >= n4) return;
    const float4 f = reinterpret_cast<const float4*>(x)[i];
    union { ushort4 u; __half2 h2[2]; } pk;
    pk.h2[0] = __floats2half2_rn(f.x, f.y);
    pk.h2[1] = __floats2half2_rn(f.z, f.w);
    const int node = i / 12;           // 12 quads per source row
    const int fg   = i % 12;
    __half* dst = (fg < 6)
        ? (xh0 + (size_t)node * HALF_F + fg * 4)
        : (xh1 + (size_t)node * HALF_F + (fg - 6) * 4);
    *reinterpret_cast<ushort4*>(dst) = pk.u;
}

__device__ __forceinline__ void fma4_h(vfloat4& acc, float v, const __half* p) {
    union { ushort4 u; __half2 h2[2]; } w;
    w.u = *reinterpret_cast<const ushort4*>(p);       // 8 B cached load (x reuse)
    const float2 f0 = __half22float2(w.h2[0]);
    const float2 f1 = __half22float2(w.h2[1]);
    acc.x += v * f0.x;
    acc.y += v * f0.y;
    acc.z += v * f1.x;
    acc.w += v * f1.y;
}

// Block g: oct = g%8 -> XCD (round-robin heuristic). oct 0-3 process
// feature-half 0, oct 4-7 half 1; rowblock = (g>>3)*4 + (oct&3).
__global__ __launch_bounds__(BLOCK) void spmm_half(
        const int* __restrict__ row_ptr,
        const int* __restrict__ cols,
        const float* __restrict__ vals,
        const __half* __restrict__ xh0,
        const __half* __restrict__ xh1,
        float* __restrict__ out,
        int n_nodes) {
    const int g   = blockIdx.x;
    const int oct = g & 7;
    const int h   = oct >> 2;                  // 0 or 1
    const int rowblock = ((g >> 3) << 2) + (oct & 3);
    const int tid = threadIdx.x;
    const int fg  = tid % TPR;                 // 0..5
    const int rib = tid / TPR;                 // 0..31
    const int r   = rowblock * RPB + rib;
    if (r >= n_nodes) return;

    const __half* __restrict__ xh = h ? xh1 : xh0;

    const int e0 = row_ptr[r];
    const int e1 = row_ptr[r + 1];

    vfloat4 acc = (vfloat4)(0.f);

    int e = e0;
    // 8-edge unroll: eight independent gather chains in flight per thread.
    for (; e + 7 < e1; e += 8) {
        int   c[8];
        float v[8];
#pragma unroll
        for (int j = 0; j < 8; ++j) { c[j] = cols[e + j]; v[j] = vals[e + j]; }
#pragma unroll
        for (int j = 0; j < 8; ++j)
            fma4_h(acc, v[j], xh + (size_t)c[j] * HALF_F + fg * 4);
    }
    for (; e + 3 < e1; e += 4) {
        int   c[4];
        float v[4];
#pragma unroll
        for (int j = 0; j < 4; ++j) { c[j] = cols[e + j]; v[j] = vals[e + j]; }
#pragma unroll
        for (int j = 0; j < 4; ++j)
            fma4_h(acc, v[j], xh + (size_t)c[j] * HALF_F + fg * 4);
    }
    for (; e < e1; ++e) {
        fma4_h(acc, vals[e], xh + (size_t)cols[e] * HALF_F + fg * 4);
    }

    __builtin_nontemporal_store(acc,
        reinterpret_cast<vfloat4*>(out + (size_t)r * D_FEAT + h * HALF_F + fg * 4));
}

// f32 fallback (used only if ws_size can't hold the fp16 copies)
__global__ __launch_bounds__(BLOCK) void spmm_rows_f32(
        const int* __restrict__ row_ptr,
        const int* __restrict__ cols,
        const float* __restrict__ vals,
        const float* __restrict__ x,
        float* __restrict__ out,
        int n_nodes) {
    const int tid = threadIdx.x;
    const int fg  = tid % 12;
    const int rib = tid / 12;
    const int r   = blockIdx.x * 16 + rib;
    if (r >= n_nodes) return;
    const int e0 = row_ptr[r];
    const int e1 = row_ptr[r + 1];
    float4 acc = make_float4(0.f, 0.f, 0.f, 0.f);
    for (int e = e0; e < e1; ++e) {
        const float v = vals[e];
        const float4 xa = *reinterpret_cast<const float4*>(
            x + (size_t)cols[e] * D_FEAT + fg * 4);
        acc.x += v * xa.x; acc.y += v * xa.y;
        acc.z += v * xa.z; acc.w += v * xa.w;
    }
    *reinterpret_cast<float4*>(out + (size_t)r * D_FEAT + fg * 4) = acc;
}

extern "C" void kernel_launch(void* const* d_in, const int* in_sizes, int n_in,
                              void* d_out, int out_size, void* d_ws, size_t ws_size,
                              hipStream_t stream) {
    // inputs: t(f32,1), x(f32,N*48), rows(i32,E), cols(i32,E), vals(f32,E)
    const float* x    = (const float*)d_in[1];
    const int*   rows = (const int*)  d_in[2];
    const int*   cols = (const int*)  d_in[3];
    const float* vals = (const float*)d_in[4];
    float*       out  = (float*)d_out;

    const int n_edges = in_sizes[2];
    const int n_x     = in_sizes[1];           // n_nodes * 48
    const int n_nodes = out_size / D_FEAT;     // 100000

    int* row_ptr = (int*)d_ws;                 // (n_nodes+1) ints
    const size_t rp_bytes   = (size_t)(n_nodes + 1) * sizeof(int);
    const size_t xh0_off    = (rp_bytes + 255) & ~(size_t)255;
    const size_t half_bytes = (size_t)n_nodes * HALF_F * sizeof(__half);
    const size_t xh1_off    = (xh0_off + half_bytes + 255) & ~(size_t)255;
    const size_t need       = xh1_off + half_bytes;

    {
        const int threads = 256;
        const int grid = (n_edges + threads - 1) / threads;
        build_row_ptr_scatter<<<grid, threads, 0, stream>>>(rows, row_ptr, n_edges, n_nodes);
    }

    if (ws_size >= need) {
        __half* xh0 = (__half*)((char*)d_ws + xh0_off);
        __half* xh1 = (__half*)((char*)d_ws + xh1_off);
        {
            const int n4 = n_x / 4;
            const int threads = 256;
            const int grid = (n4 + threads - 1) / threads;
            convert_x_f16_split<<<grid, threads, 0, stream>>>(x, xh0, xh1, n4);
        }
        // rowblocks per half, rounded to a multiple of 4 so the oct mapping
        // covers every (half, rowblock); OOB rowblocks exit via guard.
        const int nrb  = (n_nodes + RPB - 1) / RPB;        // 3125
        const int nrb4 = (nrb + 3) & ~3;                   // 3128
        const int grid = nrb4 * 2;                         // 6256
        spmm_half<<<grid, BLOCK, 0, stream>>>(row_ptr, cols, vals, xh0, xh1, out, n_nodes);
    } else {
        const int grid = (n_nodes + 15) / 16;
        spmm_rows_f32<<<grid, BLOCK, 0, stream>>>(row_ptr, cols, vals, x, out, n_nodes);
    }
}

// Round 8
// 126.934 us; speedup vs baseline: 1.0233x; 1.0233x over previous
//
#include <hip/hip_runtime.h>
#include <hip/hip_bf16.h>
#include <hip/hip_fp16.h>

// SpMM: out[r] = sum_e (rows[e]==r) vals[e] * x[cols[e], :]
// rows sorted ascending (CSR-like). N=100000, E=1600000, D=48.
//
// R8 = revert to the measured-best R6 configuration (127.4 us total).
// History of structural attempts on the gather-miss rate:
//  - R4/R5 pad fp16 rows to 128 B: REGRESSED (L2 fetches 64 B sectors, so
//    stride-96 already costs 128 B/miss; padding only grew the footprint).
//  - R7 feature-split + XCD pinning via blockIdx%8: REGRESSED (4.8 MB/XCD
//    still > 4 MB L2; doubled edge-stream + TA divergence cost more than
//    the modest hit-rate gain bought).
//  - fp8 rejected on error budget (~1.0 predicted absmax vs 0.3 threshold).
// Conclusion: spmm (~40 us) sits ~15% above the random-sector L2-miss
// throughput floor (~120 MB @ ~3.4 TB/s); the other ~85 us of dur_us is
// harness-fixed (268 MB ws poison fill + input restores).

#define D_FEAT 48
#define TPR 12          // threads per row (each owns a 4-feature slice)
#define RPB 16          // rows per block
#define BLOCK (TPR * RPB)  // 192

typedef float vfloat4 __attribute__((ext_vector_type(4)));

__global__ void build_row_ptr_scatter(const int* __restrict__ rows,
                                      int* __restrict__ row_ptr,
                                      int n_edges, int n_nodes) {
    int e = blockIdx.x * blockDim.x + threadIdx.x;
    if (e >= n_edges) return;
    const int r     = rows[e];
    const int rprev = (e == 0) ? -1 : rows[e - 1];
    for (int q = rprev + 1; q <= r; ++q) row_ptr[q] = e;
    if (e == n_edges - 1) {
        for (int q = r + 1; q <= n_nodes; ++q) row_ptr[q] = n_edges;
    }
}

// One thread per 4 source floats -> one 8 B fp16 write (dense stride 48).
__global__ void convert_x_f16(const float* __restrict__ x,
                              __half* __restrict__ xh, int n4) {
    int i = blockIdx.x * blockDim.x + threadIdx.x;
    if (i >= n4) return;
    const float4 f = reinterpret_cast<const float4*>(x)[i];
    union { ushort4 u; __half2 h2[2]; } pk;
    pk.h2[0] = __floats2half2_rn(f.x, f.y);
    pk.h2[1] = __floats2half2_rn(f.z, f.w);
    reinterpret_cast<ushort4*>(xh)[i] = pk.u;
}

__device__ __forceinline__ void fma4_h(vfloat4& acc, float v, const __half* p) {
    union { ushort4 u; __half2 h2[2]; } w;
    w.u = *reinterpret_cast<const ushort4*>(p);       // 8 B cached load (x reuse)
    const float2 f0 = __half22float2(w.h2[0]);
    const float2 f1 = __half22float2(w.h2[1]);
    acc.x += v * f0.x;
    acc.y += v * f0.y;
    acc.z += v * f1.x;
    acc.w += v * f1.y;
}

__global__ __launch_bounds__(BLOCK) void spmm_rows_f16(
        const int* __restrict__ row_ptr,
        const int* __restrict__ cols,
        const float* __restrict__ vals,
        const __half* __restrict__ xh,
        float* __restrict__ out,
        int n_nodes) {
    const int tid = threadIdx.x;
    const int fg  = tid % TPR;
    const int rib = tid / TPR;
    const int r   = blockIdx.x * RPB + rib;
    if (r >= n_nodes) return;

    const int e0 = row_ptr[r];
    const int e1 = row_ptr[r + 1];

    vfloat4 acc = (vfloat4)(0.f);

    int e = e0;
    // 8-edge unroll: eight independent gather chains in flight per thread.
    for (; e + 7 < e1; e += 8) {
        int   c[8];
        float v[8];
#pragma unroll
        for (int j = 0; j < 8; ++j) { c[j] = cols[e + j]; v[j] = vals[e + j]; }
#pragma unroll
        for (int j = 0; j < 8; ++j)
            fma4_h(acc, v[j], xh + (size_t)c[j] * D_FEAT + fg * 4);
    }
    for (; e + 3 < e1; e += 4) {
        int   c[4];
        float v[4];
#pragma unroll
        for (int j = 0; j < 4; ++j) { c[j] = cols[e + j]; v[j] = vals[e + j]; }
#pragma unroll
        for (int j = 0; j < 4; ++j)
            fma4_h(acc, v[j], xh + (size_t)c[j] * D_FEAT + fg * 4);
    }
    for (; e < e1; ++e) {
        fma4_h(acc, vals[e], xh + (size_t)cols[e] * D_FEAT + fg * 4);
    }

    __builtin_nontemporal_store(acc,
        reinterpret_cast<vfloat4*>(out + (size_t)r * D_FEAT + fg * 4));
}

// f32 fallback (used only if ws_size can't hold the fp16 copy)
__global__ __launch_bounds__(BLOCK) void spmm_rows_f32(
        const int* __restrict__ row_ptr,
        const int* __restrict__ cols,
        const float* __restrict__ vals,
        const float* __restrict__ x,
        float* __restrict__ out,
        int n_nodes) {
    const int tid = threadIdx.x;
    const int fg  = tid % TPR;
    const int rib = tid / TPR;
    const int r   = blockIdx.x * RPB + rib;
    if (r >= n_nodes) return;
    const int e0 = row_ptr[r];
    const int e1 = row_ptr[r + 1];
    float4 acc = make_float4(0.f, 0.f, 0.f, 0.f);
    for (int e = e0; e < e1; ++e) {
        const float v = vals[e];
        const float4 xa = *reinterpret_cast<const float4*>(
            x + (size_t)cols[e] * D_FEAT + fg * 4);
        acc.x += v * xa.x; acc.y += v * xa.y;
        acc.z += v * xa.z; acc.w += v * xa.w;
    }
    *reinterpret_cast<float4*>(out + (size_t)r * D_FEAT + fg * 4) = acc;
}

extern "C" void kernel_launch(void* const* d_in, const int* in_sizes, int n_in,
                              void* d_out, int out_size, void* d_ws, size_t ws_size,
                              hipStream_t stream) {
    // inputs: t(f32,1), x(f32,N*48), rows(i32,E), cols(i32,E), vals(f32,E)
    const float* x    = (const float*)d_in[1];
    const int*   rows = (const int*)  d_in[2];
    const int*   cols = (const int*)  d_in[3];
    const float* vals = (const float*)d_in[4];
    float*       out  = (float*)d_out;

    const int n_edges = in_sizes[2];
    const int n_x     = in_sizes[1];           // n_nodes * 48
    const int n_nodes = out_size / D_FEAT;     // 100000

    int* row_ptr = (int*)d_ws;                 // (n_nodes+1) ints
    const size_t rp_bytes  = (size_t)(n_nodes + 1) * sizeof(int);
    const size_t xh_off    = (rp_bytes + 255) & ~(size_t)255;
    const size_t need      = xh_off + (size_t)n_x * sizeof(__half);

    {
        const int threads = 256;
        const int grid = (n_edges + threads - 1) / threads;
        build_row_ptr_scatter<<<grid, threads, 0, stream>>>(rows, row_ptr, n_edges, n_nodes);
    }

    if (ws_size >= need) {
        __half* xh = (__half*)((char*)d_ws + xh_off);
        {
            const int n4 = n_x / 4;
            const int threads = 256;
            const int grid = (n4 + threads - 1) / threads;
            convert_x_f16<<<grid, threads, 0, stream>>>(x, xh, n4);
        }
        const int grid = (n_nodes + RPB - 1) / RPB;
        spmm_rows_f16<<<grid, BLOCK, 0, stream>>>(row_ptr, cols, vals, xh, out, n_nodes);
    } else {
        const int grid = (n_nodes + RPB - 1) / RPB;
        spmm_rows_f32<<<grid, BLOCK, 0, stream>>>(row_ptr, cols, vals, x, out, n_nodes);
    }
}